// Round 7
// baseline (634.386 us; speedup 1.0000x reference)
//
#include <hip/hip_runtime.h>
#include <hip/hip_bf16.h>

#define T_SEQ  180
#define LATENT 128
#define HIDDEN 256

typedef __attribute__((ext_vector_type(8))) short  short8;   // 8 x bf16 (4 VGPRs)
typedef __attribute__((ext_vector_type(4))) float  floatx4;  // MFMA acc

// ---- d_ws layout (ushort units) ----
#define WHH_US 196608   // fc_w pack starts here

// ---- dynamic LDS layout (bytes) ----
// [0,      131072) : w_hh n-gate frags s=4,5: ((wv*2+s2)*8+kc)*1024 B
// [131072, 147968) : h_lds 32 rows x 264 ushorts
// [147968, 151040) : obufw [3][8][16][2] float (per-wave proj partials, no atomics)
#define HLDS_OFF   131072
#define OBUF_OFF   147968
#define SMEM_BYTES 151040

__device__ __forceinline__ unsigned short f2bf(float f) {
    unsigned int u = __float_as_uint(f);
    u += 0x7fffu + ((u >> 16) & 1u);      // round-to-nearest-even
    return (unsigned short)(u >> 16);
}

__device__ __forceinline__ float sigmoid_fast(float x) {
    return __builtin_amdgcn_rcpf(1.0f + __expf(-x));
}
__device__ __forceinline__ float tanh_fast(float x) {
    // tanh(x) = 1 - 2/(e^{2x}+1); overflow-safe (e^inf -> inf -> rcp -> 0)
    return 1.0f - 2.0f * __builtin_amdgcn_rcpf(1.0f + __expf(2.0f * x));
}

// Pack w_hh [768,256] fp32 row-major -> bf16 MFMA B-fragments.
__global__ void pack_whh(const float* __restrict__ whh, unsigned short* __restrict__ dst) {
    int tid  = blockIdx.x * blockDim.x + threadIdx.x;  // 24576 threads
    int lane = tid & 63;
    int frag = tid >> 6;                               // 0..383
    int kc   = frag & 7;
    int sub  = (frag >> 3) % 6;
    int w    = frag / 48;
    int g = sub >> 1, cs = sub & 1;
    int col  = w * 32 + cs * 16 + (lane & 15);
    int jout = g * 256 + col;
    int k0   = kc * 32 + ((lane >> 4) << 3);
    const float* src = whh + jout * 256 + k0;
    unsigned int u[4];
#pragma unroll
    for (int j = 0; j < 4; ++j)
        u[j] = (unsigned int)f2bf(src[2 * j]) | ((unsigned int)f2bf(src[2 * j + 1]) << 16);
    *(uint4*)(dst + frag * 512 + lane * 8) = make_uint4(u[0], u[1], u[2], u[3]);
}

// Pack fc_w [256,128] fp32 row-major -> bf16 MFMA B-fragments.
__global__ void pack_fcw(const float* __restrict__ fcw, unsigned short* __restrict__ dst) {
    int tid  = blockIdx.x * blockDim.x + threadIdx.x;  // 4096 threads
    int lane = tid & 63;
    int frag = tid >> 6;                               // 0..63
    int kc   = frag & 3;
    int cs   = (frag >> 2) & 1;
    int w    = frag >> 3;
    int col  = w * 32 + cs * 16 + (lane & 15);
    int k0   = kc * 32 + ((lane >> 4) << 3);
    const float* src = fcw + col * 128 + k0;
    unsigned int u[4];
#pragma unroll
    for (int j = 0; j < 4; ++j)
        u[j] = (unsigned int)f2bf(src[2 * j]) | ((unsigned int)f2bf(src[2 * j + 1]) << 16);
    *(uint4*)(dst + frag * 512 + lane * 8) = make_uint4(u[0], u[1], u[2], u[3]);
}

// Persistent GRU: 256 blocks x 512 threads, 32 rows/block, wave owns 32 cols.
// r3 register layout (PROVEN no-spill): 32 weight frags in regs (128 VGPR),
// n-gate frags (s=4,5) in LDS. 2 waves/SIMD unified budget = 256 regs total
// incl. AGPRs -- 40-frag variants spill (r4/r5 evidence), do not grow.
// r7: gate-VALU units INTERLEAVED into the MFMA kc-loop (one r-unit per odd
// kc) so the wave's stream alternates MFMA/VALU and both pipes run
// concurrently (m114) -- r6 showed sum-of-pipes (93% combined), not max.
__global__ __launch_bounds__(512, 2) void gru_main(
    const float* __restrict__ z,
    const float* __restrict__ fc_b,
    const float* __restrict__ b_ih,
    const float* __restrict__ b_hh,
    const float* __restrict__ out_w,
    const float* __restrict__ out_b,
    const unsigned short* __restrict__ wpack,
    float* __restrict__ out)
{
    extern __shared__ unsigned char smem[];
    unsigned short* wlds  = (unsigned short*)smem;               // s=4,5 frags
    unsigned short* h_lds = (unsigned short*)(smem + HLDS_OFF);
    float*          obufw = (float*)(smem + OBUF_OFF);           // [3][8][16][2]

    const int tid  = threadIdx.x;
    const int lane = tid & 63;
    const int wv   = tid >> 6;
    const int l15  = lane & 15;
    const int qd   = lane >> 4;
    const int rb   = blockIdx.x * 32;

    // ---- stage n-gate weight frags (s=4,5) into LDS (16 KB per wave) ----
#pragma unroll
    for (int s2 = 0; s2 < 2; ++s2)
#pragma unroll
        for (int kc = 0; kc < 8; ++kc) {
            int gfrag = (wv * 6 + 4 + s2) * 8 + kc;
            uint4 v = *(const uint4*)(wpack + gfrag * 512 + lane * 8);
            *(uint4*)(wlds + (((wv * 2 + s2) * 8 + kc) << 9) + lane * 8) = v;
        }

    // ---- r,z-gate weight frags into registers (32 frags = 128 VGPRs) ----
    short8 wreg[32];
#pragma unroll
    for (int s = 0; s < 4; ++s)
#pragma unroll
        for (int kc = 0; kc < 8; ++kc)
            wreg[s * 8 + kc] = ((const short8*)wpack)[((wv * 6 + s) * 8 + kc) * 64 + lane];

    // ---- stage z tile into h_lds ----
    {
        int row = tid >> 4;
        int seg = tid & 15;
        const float* zp = z + (size_t)(rb + row) * LATENT + seg * 8;
        unsigned int u[4];
#pragma unroll
        for (int j = 0; j < 4; ++j)
            u[j] = (unsigned int)f2bf(zp[2 * j]) | ((unsigned int)f2bf(zp[2 * j + 1]) << 16);
        *(uint4*)&h_lds[row * 264 + seg * 8] = make_uint4(u[0], u[1], u[2], u[3]);
    }

    // ---- per-lane constants ----
    float cb[2][2], bhn[2], bin[2], fcb[2];
#pragma unroll
    for (int cs = 0; cs < 2; ++cs) {
        int col = wv * 32 + cs * 16 + l15;
        cb[0][cs] = b_ih[col]       + b_hh[col];
        cb[1][cs] = b_ih[256 + col] + b_hh[256 + col];
        bin[cs]   = b_ih[512 + col];
        bhn[cs]   = b_hh[512 + col];
        fcb[cs]   = fc_b[col];
    }
    float ob = (tid < 64) ? out_b[tid & 1] : 0.0f;

    // projection B-frag: B[k][n], k = wv*32 + qd*8 + j, n = l15 (0,1 used)
    short8 bproj;
    {
        int k0 = wv * 32 + qd * 8;
#pragma unroll
        for (int j = 0; j < 8; ++j) {
            float v = (l15 == 0) ? out_w[k0 + j] : ((l15 == 1) ? out_w[256 + k0 + j] : 0.0f);
            bproj[j] = (short)f2bf(v);
        }
    }

    __syncthreads();

    // ---- h0 = tanh(z @ fc_w^T + fc_b) ----
    floatx4 a0f[2][2];
#pragma unroll
    for (int rt = 0; rt < 2; ++rt)
#pragma unroll
        for (int cs = 0; cs < 2; ++cs)
            a0f[rt][cs] = (floatx4){0.f, 0.f, 0.f, 0.f};
#pragma unroll
    for (int kc = 0; kc < 4; ++kc) {
        short8 afr0 = *(const short8*)&h_lds[(0  + l15) * 264 + kc * 32 + qd * 8];
        short8 afr1 = *(const short8*)&h_lds[(16 + l15) * 264 + kc * 32 + qd * 8];
#pragma unroll
        for (int cs = 0; cs < 2; ++cs) {
            short8 bfr = ((const short8*)wpack)[(size_t)(WHH_US / 8) + ((wv * 2 + cs) * 4 + kc) * 64 + lane];
            a0f[0][cs] = __builtin_amdgcn_mfma_f32_16x16x32_bf16(afr0, bfr, a0f[0][cs], 0, 0, 0);
            a0f[1][cs] = __builtin_amdgcn_mfma_f32_16x16x32_bf16(afr1, bfr, a0f[1][cs], 0, 0, 0);
        }
    }

    float hm0[2][4], hm1[2][4];
#pragma unroll
    for (int cs = 0; cs < 2; ++cs)
#pragma unroll
        for (int r = 0; r < 4; ++r) {
            hm0[cs][r] = tanh_fast(a0f[0][cs][r] + fcb[cs]);
            hm1[cs][r] = tanh_fast(a0f[1][cs][r] + fcb[cs]);
        }

    __syncthreads();   // done reading z
#pragma unroll
    for (int cs = 0; cs < 2; ++cs)
#pragma unroll
        for (int r = 0; r < 4; ++r) {
            h_lds[(0  + qd * 4 + r) * 264 + wv * 32 + cs * 16 + l15] = f2bf(hm0[cs][r]);
            h_lds[(16 + qd * 4 + r) * 264 + wv * 32 + cs * 16 + l15] = f2bf(hm1[cs][r]);
        }
    __syncthreads();

    // one r-unit of gate nonlinearity + h update + LDS writeback (both cs)
    auto gate_unit = [&](floatx4* a, float (*hmH)[4], int rowbase, int r) {
        float hv[2];
#pragma unroll
        for (int cs = 0; cs < 2; ++cs) {
            float gr = sigmoid_fast(a[cs][r]);
            float gz = sigmoid_fast(a[2 + cs][r]);
            float gn = tanh_fast(bin[cs] + gr * a[4 + cs][r]);
            float h  = gn + gz * (hmH[cs][r] - gn);
            hmH[cs][r] = h;
            hv[cs] = h;
        }
        // packed f32->bf16 RNE (v_cvt_pk_bf16_f32)
        __hip_bfloat162 pk = __float22bfloat162_rn(make_float2(hv[0], hv[1]));
        union { __hip_bfloat16 b; unsigned short u; } cu0, cu1;
        cu0.b = pk.x; cu1.b = pk.y;
        int rowoff = (rowbase + qd * 4 + r) * 264 + wv * 32 + l15;
        h_lds[rowoff]      = cu0.u;
        h_lds[rowoff + 16] = cu1.u;
    };

    floatx4 acc1[6];   // loop-carried: filled in slot Y, consumed in next slot X

    // ---- 180 steps, 2 pipelined slots each ----
#pragma unroll 1
    for (int t = 0; t < T_SEQ; ++t) {
        // ======== SLOT X: MFMA rows0-15 ; interleaved gates rows16-31 ========
        floatx4 acc0[6];
#pragma unroll
        for (int s = 0; s < 6; ++s) {
            float b = (s < 4) ? cb[s >> 1][s & 1] : bhn[s & 1];
            acc0[s] = (floatx4){b, b, b, b};
        }
        if (t == 0) {
            // peeled: acc1/hm1 not yet valid, MFMA only
#pragma unroll
            for (int kc = 0; kc < 8; ++kc) {
                short8 afr = *(const short8*)&h_lds[l15 * 264 + kc * 32 + qd * 8];
#pragma unroll
                for (int s = 0; s < 4; ++s)
                    acc0[s] = __builtin_amdgcn_mfma_f32_16x16x32_bf16(afr, wreg[s * 8 + kc], acc0[s], 0, 0, 0);
                short8 b4 = *(const short8*)&wlds[(((wv * 2 + 0) * 8 + kc) << 9) + lane * 8];
                short8 b5 = *(const short8*)&wlds[(((wv * 2 + 1) * 8 + kc) << 9) + lane * 8];
                acc0[4] = __builtin_amdgcn_mfma_f32_16x16x32_bf16(afr, b4, acc0[4], 0, 0, 0);
                acc0[5] = __builtin_amdgcn_mfma_f32_16x16x32_bf16(afr, b5, acc0[5], 0, 0, 0);
            }
        } else {
#pragma unroll
            for (int kc = 0; kc < 8; ++kc) {
                short8 afr = *(const short8*)&h_lds[l15 * 264 + kc * 32 + qd * 8];
#pragma unroll
                for (int s = 0; s < 4; ++s)
                    acc0[s] = __builtin_amdgcn_mfma_f32_16x16x32_bf16(afr, wreg[s * 8 + kc], acc0[s], 0, 0, 0);
                short8 b4 = *(const short8*)&wlds[(((wv * 2 + 0) * 8 + kc) << 9) + lane * 8];
                short8 b5 = *(const short8*)&wlds[(((wv * 2 + 1) * 8 + kc) << 9) + lane * 8];
                acc0[4] = __builtin_amdgcn_mfma_f32_16x16x32_bf16(afr, b4, acc0[4], 0, 0, 0);
                acc0[5] = __builtin_amdgcn_mfma_f32_16x16x32_bf16(afr, b5, acc0[5], 0, 0, 0);
                if (kc & 1)
                    gate_unit(acc1, hm1, 16, kc >> 1);   // rows16-31 -> state t
            }
        }
        // projection partial of rows0-15 state (out idx t-1), own k-slice
        floatx4 pj0 = (floatx4){0.f, 0.f, 0.f, 0.f};
        {
            short8 afrp = *(const short8*)&h_lds[l15 * 264 + wv * 32 + qd * 8];
            pj0 = __builtin_amdgcn_mfma_f32_16x16x32_bf16(afrp, bproj, pj0, 0, 0, 0);
        }
        if (t >= 2 && tid < 32) {                 // flush bufB: out idx t-2, rows16-31
            int rl = tid >> 1, o = tid & 1;
            float s = ob;
#pragma unroll
            for (int w2 = 0; w2 < 8; ++w2) s += obufw[256 + w2 * 32 + rl * 2 + o];
            out[(size_t)(rb + 16 + rl) * (T_SEQ * 2) + (t - 2) * 2 + o] = s;
        }
        if (t >= 1 && l15 < 2) {                  // per-wave store, no atomics
#pragma unroll
            for (int r = 0; r < 4; ++r)
                obufw[wv * 32 + (qd * 4 + r) * 2 + l15] = pj0[r];
        }
        __syncthreads();

        // ======== SLOT Y: MFMA rows16-31 ; interleaved gates rows0-15 ========
#pragma unroll
        for (int s = 0; s < 6; ++s) {
            float b = (s < 4) ? cb[s >> 1][s & 1] : bhn[s & 1];
            acc1[s] = (floatx4){b, b, b, b};
        }
#pragma unroll
        for (int kc = 0; kc < 8; ++kc) {
            short8 afr = *(const short8*)&h_lds[(16 + l15) * 264 + kc * 32 + qd * 8];
#pragma unroll
            for (int s = 0; s < 4; ++s)
                acc1[s] = __builtin_amdgcn_mfma_f32_16x16x32_bf16(afr, wreg[s * 8 + kc], acc1[s], 0, 0, 0);
            short8 b4 = *(const short8*)&wlds[(((wv * 2 + 0) * 8 + kc) << 9) + lane * 8];
            short8 b5 = *(const short8*)&wlds[(((wv * 2 + 1) * 8 + kc) << 9) + lane * 8];
            acc1[4] = __builtin_amdgcn_mfma_f32_16x16x32_bf16(afr, b4, acc1[4], 0, 0, 0);
            acc1[5] = __builtin_amdgcn_mfma_f32_16x16x32_bf16(afr, b5, acc1[5], 0, 0, 0);
            if (kc & 1)
                gate_unit(acc0, hm0, 0, kc >> 1);        // rows0-15 -> state t+? (next state)
        }
        floatx4 pj1 = (floatx4){0.f, 0.f, 0.f, 0.f};
        {
            short8 afrp = *(const short8*)&h_lds[(16 + l15) * 264 + wv * 32 + qd * 8];
            pj1 = __builtin_amdgcn_mfma_f32_16x16x32_bf16(afrp, bproj, pj1, 0, 0, 0);
        }
        if (t >= 1 && tid < 32) {                 // flush bufA: out idx t-1, rows0-15
            int rl = tid >> 1, o = tid & 1;
            float s = ob;
#pragma unroll
            for (int w2 = 0; w2 < 8; ++w2) s += obufw[w2 * 32 + rl * 2 + o];
            out[(size_t)(rb + rl) * (T_SEQ * 2) + (t - 1) * 2 + o] = s;
        }
        if (t >= 1 && l15 < 2) {
#pragma unroll
            for (int r = 0; r < 4; ++r)
                obufw[256 + wv * 32 + (qd * 4 + r) * 2 + l15] = pj1[r];
        }
        __syncthreads();
    }

    // ---- epilogue: finish final rows16-31 state, project final state (out idx 179) ----
#pragma unroll
    for (int r = 0; r < 4; ++r)
        gate_unit(acc1, hm1, 16, r);              // rows16-31 final state
    if (tid < 32) {                               // flush bufB: out idx 178, rows16-31
        int rl = tid >> 1, o = tid & 1;
        float s = ob;
#pragma unroll
        for (int w2 = 0; w2 < 8; ++w2) s += obufw[256 + w2 * 32 + rl * 2 + o];
        out[(size_t)(rb + 16 + rl) * (T_SEQ * 2) + 178 * 2 + o] = s;
    }
    {   // proj of final state rows0-15 (written in last slot Y, barrier passed)
        short8 afrp = *(const short8*)&h_lds[l15 * 264 + wv * 32 + qd * 8];
        floatx4 pj = (floatx4){0.f, 0.f, 0.f, 0.f};
        pj = __builtin_amdgcn_mfma_f32_16x16x32_bf16(afrp, bproj, pj, 0, 0, 0);
        if (l15 < 2)
#pragma unroll
            for (int r = 0; r < 4; ++r)
                obufw[wv * 32 + (qd * 4 + r) * 2 + l15] = pj[r];
    }
    __syncthreads();
    {   // proj of final state rows16-31 (written by gate_units above, barrier passed)
        short8 afrp = *(const short8*)&h_lds[(16 + l15) * 264 + wv * 32 + qd * 8];
        floatx4 pj = (floatx4){0.f, 0.f, 0.f, 0.f};
        pj = __builtin_amdgcn_mfma_f32_16x16x32_bf16(afrp, bproj, pj, 0, 0, 0);
        if (l15 < 2)
#pragma unroll
            for (int r = 0; r < 4; ++r)
                obufw[512 + wv * 32 + (qd * 4 + r) * 2 + l15] = pj[r];
    }
    if (tid < 32) {                               // flush bufA: out idx 179, rows0-15
        int rl = tid >> 1, o = tid & 1;
        float s = ob;
#pragma unroll
        for (int w2 = 0; w2 < 8; ++w2) s += obufw[w2 * 32 + rl * 2 + o];
        out[(size_t)(rb + rl) * (T_SEQ * 2) + 179 * 2 + o] = s;
    }
    __syncthreads();
    if (tid < 32) {                               // flush bufC: out idx 179, rows16-31
        int rl = tid >> 1, o = tid & 1;
        float s = ob;
#pragma unroll
        for (int w2 = 0; w2 < 8; ++w2) s += obufw[512 + w2 * 32 + rl * 2 + o];
        out[(size_t)(rb + 16 + rl) * (T_SEQ * 2) + 179 * 2 + o] = s;
    }
}

extern "C" void kernel_launch(void* const* d_in, const int* in_sizes, int n_in,
                              void* d_out, int out_size, void* d_ws, size_t ws_size,
                              hipStream_t stream) {
    const float* z     = (const float*)d_in[0];
    const float* fc_w  = (const float*)d_in[1];
    const float* fc_b  = (const float*)d_in[2];
    // d_in[3] = w_ih : unused (GRU input is all-zeros, gi = b_ih)
    const float* b_ih  = (const float*)d_in[4];
    const float* w_hh  = (const float*)d_in[5];
    const float* b_hh  = (const float*)d_in[6];
    const float* out_w = (const float*)d_in[7];
    const float* out_b = (const float*)d_in[8];
    float* out = (float*)d_out;
    unsigned short* wpack = (unsigned short*)d_ws;

    hipFuncSetAttribute((const void*)gru_main,
                        hipFuncAttributeMaxDynamicSharedMemorySize, SMEM_BYTES);

    pack_whh<<<96, 256, 0, stream>>>(w_hh, wpack);
    pack_fcw<<<16, 256, 0, stream>>>(fc_w, wpack + WHH_US);
    gru_main<<<256, 512, SMEM_BYTES, stream>>>(z, fc_b, b_ih, b_hh, out_w, out_b, wpack, out);
}

// Round 8
// 614.750 us; speedup vs baseline: 1.0319x; 1.0319x over previous
//
#include <hip/hip_runtime.h>
#include <hip/hip_bf16.h>

#define T_SEQ  180
#define LATENT 128
#define HIDDEN 256

typedef __attribute__((ext_vector_type(8))) short  short8;   // 8 x bf16 (4 VGPRs)
typedef __attribute__((ext_vector_type(4))) float  floatx4;  // MFMA acc

// ---- d_ws layout (ushort units) ----
#define WHH_US 196608   // fc_w pack starts here

// ---- dynamic LDS layout (bytes) ----
// [0,      131072) : w_hh n-gate frags s=4,5: ((wv*2+s2)*8+kc)*1024 B
// [131072, 147968) : h_lds 32 rows x 264 ushorts
// [147968, 151040) : obufw [3][8][16][2] float (per-wave proj partials, no atomics)
#define HLDS_OFF   131072
#define OBUF_OFF   147968
#define SMEM_BYTES 151040

// one slot's desired schedule: 8 x [3 ds_read | 6 MFMA | 18 VALU | 1 ds_write]
// gates-VALU is data-independent of this slot's MFMA chain, so the scheduler
// may legally alternate them; without directives it clumps (r6/r7 evidence:
// MfmaUtil+VALUBusy ~= sum of phases, not max).
#define SGB_KC \
    __builtin_amdgcn_sched_group_barrier(0x100, 3, 0); \
    __builtin_amdgcn_sched_group_barrier(0x008, 6, 0); \
    __builtin_amdgcn_sched_group_barrier(0x002, 18, 0); \
    __builtin_amdgcn_sched_group_barrier(0x200, 1, 0);
#define SGB_SLOT  SGB_KC SGB_KC SGB_KC SGB_KC SGB_KC SGB_KC SGB_KC SGB_KC \
    __builtin_amdgcn_sched_group_barrier(0x100, 1, 0); \
    __builtin_amdgcn_sched_group_barrier(0x008, 1, 0);

__device__ __forceinline__ unsigned short f2bf(float f) {
    unsigned int u = __float_as_uint(f);
    u += 0x7fffu + ((u >> 16) & 1u);      // round-to-nearest-even
    return (unsigned short)(u >> 16);
}

__device__ __forceinline__ float sigmoid_fast(float x) {
    return __builtin_amdgcn_rcpf(1.0f + __expf(-x));
}
__device__ __forceinline__ float tanh_fast(float x) {
    // tanh(x) = 1 - 2/(e^{2x}+1); overflow-safe (e^inf -> inf -> rcp -> 0)
    return 1.0f - 2.0f * __builtin_amdgcn_rcpf(1.0f + __expf(2.0f * x));
}

// Pack w_hh [768,256] fp32 row-major -> bf16 MFMA B-fragments.
__global__ void pack_whh(const float* __restrict__ whh, unsigned short* __restrict__ dst) {
    int tid  = blockIdx.x * blockDim.x + threadIdx.x;  // 24576 threads
    int lane = tid & 63;
    int frag = tid >> 6;                               // 0..383
    int kc   = frag & 7;
    int sub  = (frag >> 3) % 6;
    int w    = frag / 48;
    int g = sub >> 1, cs = sub & 1;
    int col  = w * 32 + cs * 16 + (lane & 15);
    int jout = g * 256 + col;
    int k0   = kc * 32 + ((lane >> 4) << 3);
    const float* src = whh + jout * 256 + k0;
    unsigned int u[4];
#pragma unroll
    for (int j = 0; j < 4; ++j)
        u[j] = (unsigned int)f2bf(src[2 * j]) | ((unsigned int)f2bf(src[2 * j + 1]) << 16);
    *(uint4*)(dst + frag * 512 + lane * 8) = make_uint4(u[0], u[1], u[2], u[3]);
}

// Pack fc_w [256,128] fp32 row-major -> bf16 MFMA B-fragments.
__global__ void pack_fcw(const float* __restrict__ fcw, unsigned short* __restrict__ dst) {
    int tid  = blockIdx.x * blockDim.x + threadIdx.x;  // 4096 threads
    int lane = tid & 63;
    int frag = tid >> 6;                               // 0..63
    int kc   = frag & 3;
    int cs   = (frag >> 2) & 1;
    int w    = frag >> 3;
    int col  = w * 32 + cs * 16 + (lane & 15);
    int k0   = kc * 32 + ((lane >> 4) << 3);
    const float* src = fcw + col * 128 + k0;
    unsigned int u[4];
#pragma unroll
    for (int j = 0; j < 4; ++j)
        u[j] = (unsigned int)f2bf(src[2 * j]) | ((unsigned int)f2bf(src[2 * j + 1]) << 16);
    *(uint4*)(dst + frag * 512 + lane * 8) = make_uint4(u[0], u[1], u[2], u[3]);
}

// Persistent GRU: 256 blocks x 512 threads, 32 rows/block, wave owns 32 cols.
// r3 register layout (PROVEN no-spill): 32 weight frags in regs (128 VGPR),
// n-gate frags (s=4,5) in LDS. 2 waves/SIMD unified budget = 256 regs total
// incl. AGPRs -- 40-frag variants spill (r4/r5 evidence), do not grow.
// r8: sched_group_barrier forces MFMA/VALU alternation within each slot
// (r7 showed source-interleave alone is re-clumped by the scheduler).
// t==0 peel removed via identity-gate init (acc1 z-gates = +40 => sigma=1
// => h_new == h_old), keeping the slot body one scheduling region.
__global__ __launch_bounds__(512, 2) void gru_main(
    const float* __restrict__ z,
    const float* __restrict__ fc_b,
    const float* __restrict__ b_ih,
    const float* __restrict__ b_hh,
    const float* __restrict__ out_w,
    const float* __restrict__ out_b,
    const unsigned short* __restrict__ wpack,
    float* __restrict__ out)
{
    extern __shared__ unsigned char smem[];
    unsigned short* wlds  = (unsigned short*)smem;               // s=4,5 frags
    unsigned short* h_lds = (unsigned short*)(smem + HLDS_OFF);
    float*          obufw = (float*)(smem + OBUF_OFF);           // [3][8][16][2]

    const int tid  = threadIdx.x;
    const int lane = tid & 63;
    const int wv   = tid >> 6;
    const int l15  = lane & 15;
    const int qd   = lane >> 4;
    const int rb   = blockIdx.x * 32;

    // ---- stage n-gate weight frags (s=4,5) into LDS (16 KB per wave) ----
#pragma unroll
    for (int s2 = 0; s2 < 2; ++s2)
#pragma unroll
        for (int kc = 0; kc < 8; ++kc) {
            int gfrag = (wv * 6 + 4 + s2) * 8 + kc;
            uint4 v = *(const uint4*)(wpack + gfrag * 512 + lane * 8);
            *(uint4*)(wlds + (((wv * 2 + s2) * 8 + kc) << 9) + lane * 8) = v;
        }

    // ---- r,z-gate weight frags into registers (32 frags = 128 VGPRs) ----
    short8 wreg[32];
#pragma unroll
    for (int s = 0; s < 4; ++s)
#pragma unroll
        for (int kc = 0; kc < 8; ++kc)
            wreg[s * 8 + kc] = ((const short8*)wpack)[((wv * 6 + s) * 8 + kc) * 64 + lane];

    // ---- stage z tile into h_lds ----
    {
        int row = tid >> 4;
        int seg = tid & 15;
        const float* zp = z + (size_t)(rb + row) * LATENT + seg * 8;
        unsigned int u[4];
#pragma unroll
        for (int j = 0; j < 4; ++j)
            u[j] = (unsigned int)f2bf(zp[2 * j]) | ((unsigned int)f2bf(zp[2 * j + 1]) << 16);
        *(uint4*)&h_lds[row * 264 + seg * 8] = make_uint4(u[0], u[1], u[2], u[3]);
    }

    // ---- per-lane constants ----
    float cb[2][2], bhn[2], bin[2], fcb[2];
#pragma unroll
    for (int cs = 0; cs < 2; ++cs) {
        int col = wv * 32 + cs * 16 + l15;
        cb[0][cs] = b_ih[col]       + b_hh[col];
        cb[1][cs] = b_ih[256 + col] + b_hh[256 + col];
        bin[cs]   = b_ih[512 + col];
        bhn[cs]   = b_hh[512 + col];
        fcb[cs]   = fc_b[col];
    }
    float ob = (tid < 64) ? out_b[tid & 1] : 0.0f;

    // projection B-frag: B[k][n], k = wv*32 + qd*8 + j, n = l15 (0,1 used)
    short8 bproj;
    {
        int k0 = wv * 32 + qd * 8;
#pragma unroll
        for (int j = 0; j < 8; ++j) {
            float v = (l15 == 0) ? out_w[k0 + j] : ((l15 == 1) ? out_w[256 + k0 + j] : 0.0f);
            bproj[j] = (short)f2bf(v);
        }
    }

    __syncthreads();

    // ---- h0 = tanh(z @ fc_w^T + fc_b) ----
    floatx4 a0f[2][2];
#pragma unroll
    for (int rt = 0; rt < 2; ++rt)
#pragma unroll
        for (int cs = 0; cs < 2; ++cs)
            a0f[rt][cs] = (floatx4){0.f, 0.f, 0.f, 0.f};
#pragma unroll
    for (int kc = 0; kc < 4; ++kc) {
        short8 afr0 = *(const short8*)&h_lds[(0  + l15) * 264 + kc * 32 + qd * 8];
        short8 afr1 = *(const short8*)&h_lds[(16 + l15) * 264 + kc * 32 + qd * 8];
#pragma unroll
        for (int cs = 0; cs < 2; ++cs) {
            short8 bfr = ((const short8*)wpack)[(size_t)(WHH_US / 8) + ((wv * 2 + cs) * 4 + kc) * 64 + lane];
            a0f[0][cs] = __builtin_amdgcn_mfma_f32_16x16x32_bf16(afr0, bfr, a0f[0][cs], 0, 0, 0);
            a0f[1][cs] = __builtin_amdgcn_mfma_f32_16x16x32_bf16(afr1, bfr, a0f[1][cs], 0, 0, 0);
        }
    }

    float hm0[2][4], hm1[2][4];
#pragma unroll
    for (int cs = 0; cs < 2; ++cs)
#pragma unroll
        for (int r = 0; r < 4; ++r) {
            hm0[cs][r] = tanh_fast(a0f[0][cs][r] + fcb[cs]);
            hm1[cs][r] = tanh_fast(a0f[1][cs][r] + fcb[cs]);
        }

    __syncthreads();   // done reading z
#pragma unroll
    for (int cs = 0; cs < 2; ++cs)
#pragma unroll
        for (int r = 0; r < 4; ++r) {
            h_lds[(0  + qd * 4 + r) * 264 + wv * 32 + cs * 16 + l15] = f2bf(hm0[cs][r]);
            h_lds[(16 + qd * 4 + r) * 264 + wv * 32 + cs * 16 + l15] = f2bf(hm1[cs][r]);
        }
    __syncthreads();

    // one r-unit of gate nonlinearity + h update + LDS writeback (both cs)
    auto gate_unit = [&](floatx4* a, float (*hmH)[4], int rowbase, int r) {
        float hv[2];
#pragma unroll
        for (int cs = 0; cs < 2; ++cs) {
            float gr = sigmoid_fast(a[cs][r]);
            float gz = sigmoid_fast(a[2 + cs][r]);
            float gn = tanh_fast(bin[cs] + gr * a[4 + cs][r]);
            float h  = gn + gz * (hmH[cs][r] - gn);
            hmH[cs][r] = h;
            hv[cs] = h;
        }
        // packed f32->bf16 RNE (v_cvt_pk_bf16_f32)
        __hip_bfloat162 pk = __float22bfloat162_rn(make_float2(hv[0], hv[1]));
        union { __hip_bfloat16 b; unsigned short u; } cu0, cu1;
        cu0.b = pk.x; cu1.b = pk.y;
        int rowoff = (rowbase + qd * 4 + r) * 264 + wv * 32 + l15;
        h_lds[rowoff]      = cu0.u;
        h_lds[rowoff + 16] = cu1.u;
    };

    // identity-gate init: sigma(40)=1 => slot X t=0 gates rewrite h0 unchanged
    floatx4 acc1[6];
#pragma unroll
    for (int s = 0; s < 6; ++s)
        acc1[s] = (s == 2 || s == 3) ? (floatx4){40.f, 40.f, 40.f, 40.f}
                                     : (floatx4){0.f, 0.f, 0.f, 0.f};

    // ---- 180 steps, 2 pipelined slots each ----
#pragma unroll 1
    for (int t = 0; t < T_SEQ; ++t) {
        // ======== SLOT X: MFMA rows0-15 (state t-1) ; gates rows16-31 -> state t ========
        floatx4 acc0[6];
#pragma unroll
        for (int s = 0; s < 6; ++s) {
            float b = (s < 4) ? cb[s >> 1][s & 1] : bhn[s & 1];
            acc0[s] = (floatx4){b, b, b, b};
        }
#pragma unroll
        for (int kc = 0; kc < 8; ++kc) {
            short8 afr = *(const short8*)&h_lds[l15 * 264 + kc * 32 + qd * 8];
#pragma unroll
            for (int s = 0; s < 4; ++s)
                acc0[s] = __builtin_amdgcn_mfma_f32_16x16x32_bf16(afr, wreg[s * 8 + kc], acc0[s], 0, 0, 0);
            short8 b4 = *(const short8*)&wlds[(((wv * 2 + 0) * 8 + kc) << 9) + lane * 8];
            short8 b5 = *(const short8*)&wlds[(((wv * 2 + 1) * 8 + kc) << 9) + lane * 8];
            acc0[4] = __builtin_amdgcn_mfma_f32_16x16x32_bf16(afr, b4, acc0[4], 0, 0, 0);
            acc0[5] = __builtin_amdgcn_mfma_f32_16x16x32_bf16(afr, b5, acc0[5], 0, 0, 0);
        }
#pragma unroll
        for (int r = 0; r < 4; ++r)
            gate_unit(acc1, hm1, 16, r);          // rows16-31 -> state t
        // projection partial of rows0-15 state t-1 (out idx t-1), own k-slice
        floatx4 pj0 = (floatx4){0.f, 0.f, 0.f, 0.f};
        {
            short8 afrp = *(const short8*)&h_lds[l15 * 264 + wv * 32 + qd * 8];
            pj0 = __builtin_amdgcn_mfma_f32_16x16x32_bf16(afrp, bproj, pj0, 0, 0, 0);
        }
        SGB_SLOT
        if (t >= 2 && tid < 32) {                 // flush bufB: out idx t-2, rows16-31
            int rl = tid >> 1, o = tid & 1;
            float s = ob;
#pragma unroll
            for (int w2 = 0; w2 < 8; ++w2) s += obufw[256 + w2 * 32 + rl * 2 + o];
            out[(size_t)(rb + 16 + rl) * (T_SEQ * 2) + (t - 2) * 2 + o] = s;
        }
        if (t >= 1 && l15 < 2) {                  // per-wave store, no atomics
#pragma unroll
            for (int r = 0; r < 4; ++r)
                obufw[wv * 32 + (qd * 4 + r) * 2 + l15] = pj0[r];
        }
        __syncthreads();

        // ======== SLOT Y: MFMA rows16-31 (state t) ; gates rows0-15 -> state t ========
#pragma unroll
        for (int s = 0; s < 6; ++s) {
            float b = (s < 4) ? cb[s >> 1][s & 1] : bhn[s & 1];
            acc1[s] = (floatx4){b, b, b, b};
        }
#pragma unroll
        for (int kc = 0; kc < 8; ++kc) {
            short8 afr = *(const short8*)&h_lds[(16 + l15) * 264 + kc * 32 + qd * 8];
#pragma unroll
            for (int s = 0; s < 4; ++s)
                acc1[s] = __builtin_amdgcn_mfma_f32_16x16x32_bf16(afr, wreg[s * 8 + kc], acc1[s], 0, 0, 0);
            short8 b4 = *(const short8*)&wlds[(((wv * 2 + 0) * 8 + kc) << 9) + lane * 8];
            short8 b5 = *(const short8*)&wlds[(((wv * 2 + 1) * 8 + kc) << 9) + lane * 8];
            acc1[4] = __builtin_amdgcn_mfma_f32_16x16x32_bf16(afr, b4, acc1[4], 0, 0, 0);
            acc1[5] = __builtin_amdgcn_mfma_f32_16x16x32_bf16(afr, b5, acc1[5], 0, 0, 0);
        }
#pragma unroll
        for (int r = 0; r < 4; ++r)
            gate_unit(acc0, hm0, 0, r);           // rows0-15 -> state t
        floatx4 pj1 = (floatx4){0.f, 0.f, 0.f, 0.f};
        {
            short8 afrp = *(const short8*)&h_lds[(16 + l15) * 264 + wv * 32 + qd * 8];
            pj1 = __builtin_amdgcn_mfma_f32_16x16x32_bf16(afrp, bproj, pj1, 0, 0, 0);
        }
        SGB_SLOT
        if (t >= 1 && tid < 32) {                 // flush bufA: out idx t-1, rows0-15
            int rl = tid >> 1, o = tid & 1;
            float s = ob;
#pragma unroll
            for (int w2 = 0; w2 < 8; ++w2) s += obufw[w2 * 32 + rl * 2 + o];
            out[(size_t)(rb + rl) * (T_SEQ * 2) + (t - 1) * 2 + o] = s;
        }
        if (t >= 1 && l15 < 2) {
#pragma unroll
            for (int r = 0; r < 4; ++r)
                obufw[256 + wv * 32 + (qd * 4 + r) * 2 + l15] = pj1[r];
        }
        __syncthreads();
    }

    // ---- epilogue: finish final rows16-31 state, project final state (out idx 179) ----
#pragma unroll
    for (int r = 0; r < 4; ++r)
        gate_unit(acc1, hm1, 16, r);              // rows16-31 final state
    if (tid < 32) {                               // flush bufB: out idx 178, rows16-31
        int rl = tid >> 1, o = tid & 1;
        float s = ob;
#pragma unroll
        for (int w2 = 0; w2 < 8; ++w2) s += obufw[256 + w2 * 32 + rl * 2 + o];
        out[(size_t)(rb + 16 + rl) * (T_SEQ * 2) + 178 * 2 + o] = s;
    }
    {   // proj of final state rows0-15 (written in last slot Y, barrier passed)
        short8 afrp = *(const short8*)&h_lds[l15 * 264 + wv * 32 + qd * 8];
        floatx4 pj = (floatx4){0.f, 0.f, 0.f, 0.f};
        pj = __builtin_amdgcn_mfma_f32_16x16x32_bf16(afrp, bproj, pj, 0, 0, 0);
        if (l15 < 2)
#pragma unroll
            for (int r = 0; r < 4; ++r)
                obufw[wv * 32 + (qd * 4 + r) * 2 + l15] = pj[r];
    }
    __syncthreads();
    {   // proj of final state rows16-31 (written by gate_units above, barrier passed)
        short8 afrp = *(const short8*)&h_lds[(16 + l15) * 264 + wv * 32 + qd * 8];
        floatx4 pj = (floatx4){0.f, 0.f, 0.f, 0.f};
        pj = __builtin_amdgcn_mfma_f32_16x16x32_bf16(afrp, bproj, pj, 0, 0, 0);
        if (l15 < 2)
#pragma unroll
            for (int r = 0; r < 4; ++r)
                obufw[512 + wv * 32 + (qd * 4 + r) * 2 + l15] = pj[r];
    }
    if (tid < 32) {                               // flush bufA: out idx 179, rows0-15
        int rl = tid >> 1, o = tid & 1;
        float s = ob;
#pragma unroll
        for (int w2 = 0; w2 < 8; ++w2) s += obufw[w2 * 32 + rl * 2 + o];
        out[(size_t)(rb + rl) * (T_SEQ * 2) + 179 * 2 + o] = s;
    }
    __syncthreads();
    if (tid < 32) {                               // flush bufC: out idx 179, rows16-31
        int rl = tid >> 1, o = tid & 1;
        float s = ob;
#pragma unroll
        for (int w2 = 0; w2 < 8; ++w2) s += obufw[512 + w2 * 32 + rl * 2 + o];
        out[(size_t)(rb + 16 + rl) * (T_SEQ * 2) + 179 * 2 + o] = s;
    }
}

extern "C" void kernel_launch(void* const* d_in, const int* in_sizes, int n_in,
                              void* d_out, int out_size, void* d_ws, size_t ws_size,
                              hipStream_t stream) {
    const float* z     = (const float*)d_in[0];
    const float* fc_w  = (const float*)d_in[1];
    const float* fc_b  = (const float*)d_in[2];
    // d_in[3] = w_ih : unused (GRU input is all-zeros, gi = b_ih)
    const float* b_ih  = (const float*)d_in[4];
    const float* w_hh  = (const float*)d_in[5];
    const float* b_hh  = (const float*)d_in[6];
    const float* out_w = (const float*)d_in[7];
    const float* out_b = (const float*)d_in[8];
    float* out = (float*)d_out;
    unsigned short* wpack = (unsigned short*)d_ws;

    hipFuncSetAttribute((const void*)gru_main,
                        hipFuncAttributeMaxDynamicSharedMemorySize, SMEM_BYTES);

    pack_whh<<<96, 256, 0, stream>>>(w_hh, wpack);
    pack_fcw<<<16, 256, 0, stream>>>(fc_w, wpack + WHH_US);
    gru_main<<<256, 512, SMEM_BYTES, stream>>>(z, fc_b, b_ih, b_hh, out_w, out_b, wpack, out);
}

// Round 9
// 587.172 us; speedup vs baseline: 1.0804x; 1.0470x over previous
//
#include <hip/hip_runtime.h>
#include <hip/hip_bf16.h>

#define T_SEQ  180
#define LATENT 128
#define HIDDEN 256

typedef __attribute__((ext_vector_type(8))) short  short8;   // 8 x bf16 (4 VGPRs)
typedef __attribute__((ext_vector_type(4))) float  floatx4;  // MFMA acc

// ---- d_ws layout (ushort units) ----
#define WHH_US 196608   // fc_w pack starts here

// ---- dynamic LDS layout (bytes) ----
// [0,      131072) : w_hh n-gate frags s=4,5: ((wv*2+s2)*8+kc)*1024 B
// [131072, 147968) : h_lds 32 rows x 264 ushorts
// [147968, 151040) : obufw [3][8][16][2] float (per-wave proj partials, no atomics)
#define HLDS_OFF   131072
#define OBUF_OFF   147968
#define SMEM_BYTES 151040

__device__ __forceinline__ unsigned short f2bf(float f) {
    unsigned int u = __float_as_uint(f);
    u += 0x7fffu + ((u >> 16) & 1u);      // round-to-nearest-even
    return (unsigned short)(u >> 16);
}

__device__ __forceinline__ float sigmoid_fast(float x) {
    return __builtin_amdgcn_rcpf(1.0f + __expf(-x));
}
__device__ __forceinline__ float tanh_fast(float x) {
    // tanh(x) = 1 - 2/(e^{2x}+1); overflow-safe (e^inf -> inf -> rcp -> 0)
    return 1.0f - 2.0f * __builtin_amdgcn_rcpf(1.0f + __expf(2.0f * x));
}

// Pack w_hh [768,256] fp32 row-major -> bf16 MFMA B-fragments.
__global__ void pack_whh(const float* __restrict__ whh, unsigned short* __restrict__ dst) {
    int tid  = blockIdx.x * blockDim.x + threadIdx.x;  // 24576 threads
    int lane = tid & 63;
    int frag = tid >> 6;                               // 0..383
    int kc   = frag & 7;
    int sub  = (frag >> 3) % 6;
    int w    = frag / 48;
    int g = sub >> 1, cs = sub & 1;
    int col  = w * 32 + cs * 16 + (lane & 15);
    int jout = g * 256 + col;
    int k0   = kc * 32 + ((lane >> 4) << 3);
    const float* src = whh + jout * 256 + k0;
    unsigned int u[4];
#pragma unroll
    for (int j = 0; j < 4; ++j)
        u[j] = (unsigned int)f2bf(src[2 * j]) | ((unsigned int)f2bf(src[2 * j + 1]) << 16);
    *(uint4*)(dst + frag * 512 + lane * 8) = make_uint4(u[0], u[1], u[2], u[3]);
}

// Pack fc_w [256,128] fp32 row-major -> bf16 MFMA B-fragments.
__global__ void pack_fcw(const float* __restrict__ fcw, unsigned short* __restrict__ dst) {
    int tid  = blockIdx.x * blockDim.x + threadIdx.x;  // 4096 threads
    int lane = tid & 63;
    int frag = tid >> 6;                               // 0..63
    int kc   = frag & 3;
    int cs   = (frag >> 2) & 1;
    int w    = frag >> 3;
    int col  = w * 32 + cs * 16 + (lane & 15);
    int k0   = kc * 32 + ((lane >> 4) << 3);
    const float* src = fcw + col * 128 + k0;
    unsigned int u[4];
#pragma unroll
    for (int j = 0; j < 4; ++j)
        u[j] = (unsigned int)f2bf(src[2 * j]) | ((unsigned int)f2bf(src[2 * j + 1]) << 16);
    *(uint4*)(dst + frag * 512 + lane * 8) = make_uint4(u[0], u[1], u[2], u[3]);
}

// Persistent GRU: 256 blocks x 512 threads, 32 rows/block, wave owns 32 cols.
// r3 register layout (PROVEN no-spill): 32 weight frags in regs, n-gate frags
// (s=4,5) in LDS. 2 waves/SIMD unified budget = 256 regs total incl. AGPRs --
// 40-frag variants spill (r4/r5 evidence), do not grow.
// r9 ANTI-PHASE: waves 0-3 run each slot as [MFMA -> gates]; waves 4-7 as
// [gates -> MFMA]. Waves wv and wv+4 share a SIMD (round-robin i%4), so each
// SIMD always has one wave feeding the matrix pipe and one feeding VALU ->
// cross-wave co-issue (m114). r7/r8 proved intra-wave interleave cannot
// co-issue (1 instr/cy/wave); de-correlating the pair is the fix.
__global__ __launch_bounds__(512, 2) void gru_main(
    const float* __restrict__ z,
    const float* __restrict__ fc_b,
    const float* __restrict__ b_ih,
    const float* __restrict__ b_hh,
    const float* __restrict__ out_w,
    const float* __restrict__ out_b,
    const unsigned short* __restrict__ wpack,
    float* __restrict__ out)
{
    extern __shared__ unsigned char smem[];
    unsigned short* wlds  = (unsigned short*)smem;               // s=4,5 frags
    unsigned short* h_lds = (unsigned short*)(smem + HLDS_OFF);
    float*          obufw = (float*)(smem + OBUF_OFF);           // [3][8][16][2]

    const int tid  = threadIdx.x;
    const int lane = tid & 63;
    const int wv   = tid >> 6;
    const int grp  = (wv >> 2) & 1;  // 0: waves 0-3, 1: waves 4-7 (SIMD partners)
    const int l15  = lane & 15;
    const int qd   = lane >> 4;
    const int rb   = blockIdx.x * 32;

    // ---- stage n-gate weight frags (s=4,5) into LDS (16 KB per wave) ----
#pragma unroll
    for (int s2 = 0; s2 < 2; ++s2)
#pragma unroll
        for (int kc = 0; kc < 8; ++kc) {
            int gfrag = (wv * 6 + 4 + s2) * 8 + kc;
            uint4 v = *(const uint4*)(wpack + gfrag * 512 + lane * 8);
            *(uint4*)(wlds + (((wv * 2 + s2) * 8 + kc) << 9) + lane * 8) = v;
        }

    // ---- r,z-gate weight frags into registers (32 frags = 128 VGPRs) ----
    short8 wreg[32];
#pragma unroll
    for (int s = 0; s < 4; ++s)
#pragma unroll
        for (int kc = 0; kc < 8; ++kc)
            wreg[s * 8 + kc] = ((const short8*)wpack)[((wv * 6 + s) * 8 + kc) * 64 + lane];

    // ---- stage z tile into h_lds ----
    {
        int row = tid >> 4;
        int seg = tid & 15;
        const float* zp = z + (size_t)(rb + row) * LATENT + seg * 8;
        unsigned int u[4];
#pragma unroll
        for (int j = 0; j < 4; ++j)
            u[j] = (unsigned int)f2bf(zp[2 * j]) | ((unsigned int)f2bf(zp[2 * j + 1]) << 16);
        *(uint4*)&h_lds[row * 264 + seg * 8] = make_uint4(u[0], u[1], u[2], u[3]);
    }

    // ---- per-lane constants ----
    float cb[2][2], bhn[2], bin[2], fcb[2];
#pragma unroll
    for (int cs = 0; cs < 2; ++cs) {
        int col = wv * 32 + cs * 16 + l15;
        cb[0][cs] = b_ih[col]       + b_hh[col];
        cb[1][cs] = b_ih[256 + col] + b_hh[256 + col];
        bin[cs]   = b_ih[512 + col];
        bhn[cs]   = b_hh[512 + col];
        fcb[cs]   = fc_b[col];
    }
    float ob = (tid < 64) ? out_b[tid & 1] : 0.0f;

    // projection B-frag: B[k][n], k = wv*32 + qd*8 + j, n = l15 (0,1 used)
    short8 bproj;
    {
        int k0 = wv * 32 + qd * 8;
#pragma unroll
        for (int j = 0; j < 8; ++j) {
            float v = (l15 == 0) ? out_w[k0 + j] : ((l15 == 1) ? out_w[256 + k0 + j] : 0.0f);
            bproj[j] = (short)f2bf(v);
        }
    }

    __syncthreads();

    // ---- h0 = tanh(z @ fc_w^T + fc_b) ----
    floatx4 a0f[2][2];
#pragma unroll
    for (int rt = 0; rt < 2; ++rt)
#pragma unroll
        for (int cs = 0; cs < 2; ++cs)
            a0f[rt][cs] = (floatx4){0.f, 0.f, 0.f, 0.f};
#pragma unroll
    for (int kc = 0; kc < 4; ++kc) {
        short8 afr0 = *(const short8*)&h_lds[(0  + l15) * 264 + kc * 32 + qd * 8];
        short8 afr1 = *(const short8*)&h_lds[(16 + l15) * 264 + kc * 32 + qd * 8];
#pragma unroll
        for (int cs = 0; cs < 2; ++cs) {
            short8 bfr = ((const short8*)wpack)[(size_t)(WHH_US / 8) + ((wv * 2 + cs) * 4 + kc) * 64 + lane];
            a0f[0][cs] = __builtin_amdgcn_mfma_f32_16x16x32_bf16(afr0, bfr, a0f[0][cs], 0, 0, 0);
            a0f[1][cs] = __builtin_amdgcn_mfma_f32_16x16x32_bf16(afr1, bfr, a0f[1][cs], 0, 0, 0);
        }
    }

    float hm0[2][4], hm1[2][4];
#pragma unroll
    for (int cs = 0; cs < 2; ++cs)
#pragma unroll
        for (int r = 0; r < 4; ++r) {
            hm0[cs][r] = tanh_fast(a0f[0][cs][r] + fcb[cs]);
            hm1[cs][r] = tanh_fast(a0f[1][cs][r] + fcb[cs]);
        }

    __syncthreads();   // done reading z
#pragma unroll
    for (int cs = 0; cs < 2; ++cs)
#pragma unroll
        for (int r = 0; r < 4; ++r) {
            h_lds[(0  + qd * 4 + r) * 264 + wv * 32 + cs * 16 + l15] = f2bf(hm0[cs][r]);
            h_lds[(16 + qd * 4 + r) * 264 + wv * 32 + cs * 16 + l15] = f2bf(hm1[cs][r]);
        }
    __syncthreads();

    // one r-unit of gate nonlinearity + h update + LDS writeback (both cs)
    auto gate_unit = [&](floatx4* a, float (*hmH)[4], int rowbase, int r) {
        float hv[2];
#pragma unroll
        for (int cs = 0; cs < 2; ++cs) {
            float gr = sigmoid_fast(a[cs][r]);
            float gz = sigmoid_fast(a[2 + cs][r]);
            float gn = tanh_fast(bin[cs] + gr * a[4 + cs][r]);
            float h  = gn + gz * (hmH[cs][r] - gn);
            hmH[cs][r] = h;
            hv[cs] = h;
        }
        // packed f32->bf16 RNE (v_cvt_pk_bf16_f32)
        __hip_bfloat162 pk = __float22bfloat162_rn(make_float2(hv[0], hv[1]));
        union { __hip_bfloat16 b; unsigned short u; } cu0, cu1;
        cu0.b = pk.x; cu1.b = pk.y;
        int rowoff = (rowbase + qd * 4 + r) * 264 + wv * 32 + l15;
        h_lds[rowoff]      = cu0.u;
        h_lds[rowoff + 16] = cu1.u;
    };

    // identity-gate init: sigma(40)=1 => slot X t=0 gates rewrite h0 unchanged
    floatx4 acc1[6];
#pragma unroll
    for (int s = 0; s < 6; ++s)
        acc1[s] = (s == 2 || s == 3) ? (floatx4){40.f, 40.f, 40.f, 40.f}
                                     : (floatx4){0.f, 0.f, 0.f, 0.f};

    floatx4 acc0[6];

    // ---- 180 steps, 2 anti-phased slots each ----
#pragma unroll 1
    for (int t = 0; t < T_SEQ; ++t) {
        // ======== SLOT X: MFMA rows0-15 (state t-1) ; gates rows16-31 -> state t ========
        auto mfmaX = [&]() {
#pragma unroll
            for (int s = 0; s < 6; ++s) {
                float b = (s < 4) ? cb[s >> 1][s & 1] : bhn[s & 1];
                acc0[s] = (floatx4){b, b, b, b};
            }
#pragma unroll
            for (int kc = 0; kc < 8; ++kc) {
                short8 afr = *(const short8*)&h_lds[l15 * 264 + kc * 32 + qd * 8];
#pragma unroll
                for (int s = 0; s < 4; ++s)
                    acc0[s] = __builtin_amdgcn_mfma_f32_16x16x32_bf16(afr, wreg[s * 8 + kc], acc0[s], 0, 0, 0);
                short8 b4 = *(const short8*)&wlds[(((wv * 2 + 0) * 8 + kc) << 9) + lane * 8];
                short8 b5 = *(const short8*)&wlds[(((wv * 2 + 1) * 8 + kc) << 9) + lane * 8];
                acc0[4] = __builtin_amdgcn_mfma_f32_16x16x32_bf16(afr, b4, acc0[4], 0, 0, 0);
                acc0[5] = __builtin_amdgcn_mfma_f32_16x16x32_bf16(afr, b5, acc0[5], 0, 0, 0);
            }
        };
        auto gatesX = [&]() {
#pragma unroll
            for (int r = 0; r < 4; ++r)
                gate_unit(acc1, hm1, 16, r);      // rows16-31 -> state t
        };
        if (grp == 0) { mfmaX(); gatesX(); }       // wave-uniform branch
        else          { gatesX(); mfmaX(); }       // SIMD partner runs opposite order
        // projection partial of rows0-15 state t-1 (out idx t-1), own k-slice
        floatx4 pj0 = (floatx4){0.f, 0.f, 0.f, 0.f};
        {
            short8 afrp = *(const short8*)&h_lds[l15 * 264 + wv * 32 + qd * 8];
            pj0 = __builtin_amdgcn_mfma_f32_16x16x32_bf16(afrp, bproj, pj0, 0, 0, 0);
        }
        if (t >= 2 && tid < 32) {                 // flush bufB: out idx t-2, rows16-31
            int rl = tid >> 1, o = tid & 1;
            float s = ob;
#pragma unroll
            for (int w2 = 0; w2 < 8; ++w2) s += obufw[256 + w2 * 32 + rl * 2 + o];
            out[(size_t)(rb + 16 + rl) * (T_SEQ * 2) + (t - 2) * 2 + o] = s;
        }
        if (t >= 1 && l15 < 2) {                  // per-wave store, no atomics
#pragma unroll
            for (int r = 0; r < 4; ++r)
                obufw[wv * 32 + (qd * 4 + r) * 2 + l15] = pj0[r];
        }
        __syncthreads();

        // ======== SLOT Y: MFMA rows16-31 (state t) ; gates rows0-15 -> state t ========
        auto mfmaY = [&]() {
#pragma unroll
            for (int s = 0; s < 6; ++s) {
                float b = (s < 4) ? cb[s >> 1][s & 1] : bhn[s & 1];
                acc1[s] = (floatx4){b, b, b, b};
            }
#pragma unroll
            for (int kc = 0; kc < 8; ++kc) {
                short8 afr = *(const short8*)&h_lds[(16 + l15) * 264 + kc * 32 + qd * 8];
#pragma unroll
                for (int s = 0; s < 4; ++s)
                    acc1[s] = __builtin_amdgcn_mfma_f32_16x16x32_bf16(afr, wreg[s * 8 + kc], acc1[s], 0, 0, 0);
                short8 b4 = *(const short8*)&wlds[(((wv * 2 + 0) * 8 + kc) << 9) + lane * 8];
                short8 b5 = *(const short8*)&wlds[(((wv * 2 + 1) * 8 + kc) << 9) + lane * 8];
                acc1[4] = __builtin_amdgcn_mfma_f32_16x16x32_bf16(afr, b4, acc1[4], 0, 0, 0);
                acc1[5] = __builtin_amdgcn_mfma_f32_16x16x32_bf16(afr, b5, acc1[5], 0, 0, 0);
            }
        };
        auto gatesY = [&]() {
#pragma unroll
            for (int r = 0; r < 4; ++r)
                gate_unit(acc0, hm0, 0, r);       // rows0-15 -> state t
        };
        if (grp == 0) { mfmaY(); gatesY(); }
        else          { gatesY(); mfmaY(); }
        floatx4 pj1 = (floatx4){0.f, 0.f, 0.f, 0.f};
        {
            short8 afrp = *(const short8*)&h_lds[(16 + l15) * 264 + wv * 32 + qd * 8];
            pj1 = __builtin_amdgcn_mfma_f32_16x16x32_bf16(afrp, bproj, pj1, 0, 0, 0);
        }
        if (t >= 1 && tid < 32) {                 // flush bufA: out idx t-1, rows0-15
            int rl = tid >> 1, o = tid & 1;
            float s = ob;
#pragma unroll
            for (int w2 = 0; w2 < 8; ++w2) s += obufw[w2 * 32 + rl * 2 + o];
            out[(size_t)(rb + rl) * (T_SEQ * 2) + (t - 1) * 2 + o] = s;
        }
        if (t >= 1 && l15 < 2) {
#pragma unroll
            for (int r = 0; r < 4; ++r)
                obufw[256 + wv * 32 + (qd * 4 + r) * 2 + l15] = pj1[r];
        }
        __syncthreads();
    }

    // ---- epilogue: finish final rows16-31 state, project final state (out idx 179) ----
#pragma unroll
    for (int r = 0; r < 4; ++r)
        gate_unit(acc1, hm1, 16, r);              // rows16-31 final state
    if (tid < 32) {                               // flush bufB: out idx 178, rows16-31
        int rl = tid >> 1, o = tid & 1;
        float s = ob;
#pragma unroll
        for (int w2 = 0; w2 < 8; ++w2) s += obufw[256 + w2 * 32 + rl * 2 + o];
        out[(size_t)(rb + 16 + rl) * (T_SEQ * 2) + 178 * 2 + o] = s;
    }
    {   // proj of final state rows0-15 (written in last slot Y, barrier passed)
        short8 afrp = *(const short8*)&h_lds[l15 * 264 + wv * 32 + qd * 8];
        floatx4 pj = (floatx4){0.f, 0.f, 0.f, 0.f};
        pj = __builtin_amdgcn_mfma_f32_16x16x32_bf16(afrp, bproj, pj, 0, 0, 0);
        if (l15 < 2)
#pragma unroll
            for (int r = 0; r < 4; ++r)
                obufw[wv * 32 + (qd * 4 + r) * 2 + l15] = pj[r];
    }
    __syncthreads();
    {   // proj of final state rows16-31 (written by gate_units above, barrier passed)
        short8 afrp = *(const short8*)&h_lds[(16 + l15) * 264 + wv * 32 + qd * 8];
        floatx4 pj = (floatx4){0.f, 0.f, 0.f, 0.f};
        pj = __builtin_amdgcn_mfma_f32_16x16x32_bf16(afrp, bproj, pj, 0, 0, 0);
        if (l15 < 2)
#pragma unroll
            for (int r = 0; r < 4; ++r)
                obufw[512 + wv * 32 + (qd * 4 + r) * 2 + l15] = pj[r];
    }
    if (tid < 32) {                               // flush bufA: out idx 179, rows0-15
        int rl = tid >> 1, o = tid & 1;
        float s = ob;
#pragma unroll
        for (int w2 = 0; w2 < 8; ++w2) s += obufw[w2 * 32 + rl * 2 + o];
        out[(size_t)(rb + rl) * (T_SEQ * 2) + 179 * 2 + o] = s;
    }
    __syncthreads();
    if (tid < 32) {                               // flush bufC: out idx 179, rows16-31
        int rl = tid >> 1, o = tid & 1;
        float s = ob;
#pragma unroll
        for (int w2 = 0; w2 < 8; ++w2) s += obufw[512 + w2 * 32 + rl * 2 + o];
        out[(size_t)(rb + 16 + rl) * (T_SEQ * 2) + 179 * 2 + o] = s;
    }
}

extern "C" void kernel_launch(void* const* d_in, const int* in_sizes, int n_in,
                              void* d_out, int out_size, void* d_ws, size_t ws_size,
                              hipStream_t stream) {
    const float* z     = (const float*)d_in[0];
    const float* fc_w  = (const float*)d_in[1];
    const float* fc_b  = (const float*)d_in[2];
    // d_in[3] = w_ih : unused (GRU input is all-zeros, gi = b_ih)
    const float* b_ih  = (const float*)d_in[4];
    const float* w_hh  = (const float*)d_in[5];
    const float* b_hh  = (const float*)d_in[6];
    const float* out_w = (const float*)d_in[7];
    const float* out_b = (const float*)d_in[8];
    float* out = (float*)d_out;
    unsigned short* wpack = (unsigned short*)d_ws;

    hipFuncSetAttribute((const void*)gru_main,
                        hipFuncAttributeMaxDynamicSharedMemorySize, SMEM_BYTES);

    pack_whh<<<96, 256, 0, stream>>>(w_hh, wpack);
    pack_fcw<<<16, 256, 0, stream>>>(fc_w, wpack + WHH_US);
    gru_main<<<256, 512, SMEM_BYTES, stream>>>(z, fc_b, b_ih, b_hh, out_w, out_b, wpack, out);
}